// Round 1
// baseline (597.157 us; speedup 1.0000x reference)
//
#include <hip/hip_runtime.h>
#include <hip/hip_bf16.h>
#include <cstdint>
#include <cstddef>

#define NTOK 8192
#define DMODEL 1024
#define DFF 4096
#define NEXP 8
#define CAP 2048
#define BM 128
#define BN 128
#define BK 64

typedef __attribute__((ext_vector_type(8))) __bf16 bf16x8;
typedef __attribute__((ext_vector_type(4))) float f32x4;

__device__ __forceinline__ void gload16(const void* g, void* l) {
  __builtin_amdgcn_global_load_lds(
      (__attribute__((address_space(1))) void*)(g),
      (__attribute__((address_space(3))) void*)(l),
      16, 0, 0);
}

__global__ __launch_bounds__(256) void zero_f32(float* p, int n4) {
  int i = blockIdx.x * blockDim.x + threadIdx.x;
  int stride = gridDim.x * blockDim.x;
  float4 z = make_float4(0.f, 0.f, 0.f, 0.f);
  for (; i < n4; i += stride) ((float4*)p)[i] = z;
}

// Router: scores = softmax(x @ Wr) per token (fp32, exact), also convert x -> bf16.
// One wave per token.
__global__ __launch_bounds__(256) void router_kernel(
    const float* __restrict__ x, const float* __restrict__ Wr,
    float* __restrict__ scoresT, __hip_bfloat16* __restrict__ xb) {
  const int lane = threadIdx.x & 63;
  const int t = blockIdx.x * 4 + (threadIdx.x >> 6);
  const float* xr = x + (size_t)t * DMODEL;
  float acc[NEXP];
#pragma unroll
  for (int j = 0; j < NEXP; ++j) acc[j] = 0.f;
#pragma unroll
  for (int it = 0; it < DMODEL / 64; ++it) {
    int d = it * 64 + lane;
    float xv = xr[d];
    xb[(size_t)t * DMODEL + d] = __float2bfloat16(xv);
    const float4* w = (const float4*)(Wr + (size_t)d * NEXP);
    float4 w0 = w[0], w1 = w[1];
    acc[0] += xv * w0.x; acc[1] += xv * w0.y; acc[2] += xv * w0.z; acc[3] += xv * w0.w;
    acc[4] += xv * w1.x; acc[5] += xv * w1.y; acc[6] += xv * w1.z; acc[7] += xv * w1.w;
  }
#pragma unroll
  for (int off = 32; off; off >>= 1) {
#pragma unroll
    for (int j = 0; j < NEXP; ++j) acc[j] += __shfl_xor(acc[j], off);
  }
  float m = acc[0];
#pragma unroll
  for (int j = 1; j < NEXP; ++j) m = fmaxf(m, acc[j]);
  float s = 0.f;
#pragma unroll
  for (int j = 0; j < NEXP; ++j) { acc[j] = expf(acc[j] - m); s += acc[j]; }
  float inv = 1.f / s;
  if (lane < NEXP) scoresT[(size_t)lane * NTOK + t] = acc[lane] * inv;
}

// Exact top-k=CAP per expert via 4-round radix-8 select on the fp32 bit pattern
// (scores > 0 so u32 bit order == float order). Tie-break: lowest index first
// (matches jax.lax.top_k). Output order within an expert is irrelevant.
__global__ __launch_bounds__(256) void topk_kernel(
    const float* __restrict__ scoresT, float* __restrict__ G, int* __restrict__ IDX) {
  __shared__ uint32_t sb[NTOK];
  __shared__ uint32_t hist[256];
  __shared__ uint32_t s_prefix, s_rem;
  __shared__ uint32_t eq_list[256];
  __shared__ uint32_t eq_cnt, gt_cnt;
  const int e = blockIdx.x, tid = threadIdx.x;
  const float* se = scoresT + (size_t)e * NTOK;
  for (int i = tid; i < NTOK; i += 256) sb[i] = __float_as_uint(se[i]);
  if (tid == 0) { s_prefix = 0u; s_rem = CAP; eq_cnt = 0u; gt_cnt = 0u; }
  __syncthreads();
  for (int r = 0; r < 4; ++r) {
    const int shift = 24 - 8 * r;
    for (int i = tid; i < 256; i += 256) hist[i] = 0u;
    __syncthreads();
    uint32_t pfx = s_prefix;
    for (int i = tid; i < NTOK; i += 256) {
      uint32_t b = sb[i];
      if (((b >> shift) >> 8) == pfx) atomicAdd(&hist[(b >> shift) & 255u], 1u);
    }
    __syncthreads();
    if (tid == 0) {
      uint32_t rem = s_rem, cum = 0u;
      int d = 255;
      for (; d > 0; --d) {
        if (cum + hist[d] >= rem) break;
        cum += hist[d];
      }
      s_prefix = (pfx << 8) | (uint32_t)d;
      s_rem = rem - cum;
    }
    __syncthreads();
  }
  const uint32_t T = s_prefix, need = s_rem;
  for (int i = tid; i < NTOK; i += 256) {
    uint32_t b = sb[i];
    if (b > T) {
      uint32_t p = atomicAdd(&gt_cnt, 1u);
      IDX[(size_t)e * CAP + p] = i;
      G[(size_t)e * CAP + p] = __uint_as_float(b);
    } else if (b == T) {
      uint32_t c = atomicAdd(&eq_cnt, 1u);
      if (c < 256u) eq_list[c] = (uint32_t)i;
    }
  }
  __syncthreads();
  if (tid == 0) {
    uint32_t base = gt_cnt;
    uint32_t c = eq_cnt < 256u ? eq_cnt : 256u;
    for (uint32_t s = 0; s < need; ++s) {
      uint32_t mv = 0xFFFFFFFFu; int mi = 0;
      for (uint32_t j = 0; j < c; ++j)
        if (eq_list[j] < mv) { mv = eq_list[j]; mi = (int)j; }
      eq_list[mi] = 0xFFFFFFFFu;
      IDX[(size_t)e * CAP + base + s] = (int)mv;
      G[(size_t)e * CAP + base + s] = __uint_as_float(T);
    }
  }
}

// Transpose + fp32->bf16: in [E][R][C] -> out [E][C][R]
__global__ __launch_bounds__(256) void transpose_cvt(
    const float* __restrict__ in, __hip_bfloat16* __restrict__ out, int R, int C) {
  __shared__ float tile[32][33];
  const int e = blockIdx.z;
  const float* ine = in + (size_t)e * R * C;
  __hip_bfloat16* oute = out + (size_t)e * R * C;
  const int c0 = blockIdx.x * 32, r0 = blockIdx.y * 32;
  const int tx = threadIdx.x, ty = threadIdx.y;
#pragma unroll
  for (int i = 0; i < 4; ++i)
    tile[ty + i * 8][tx] = ine[(size_t)(r0 + ty + i * 8) * C + (c0 + tx)];
  __syncthreads();
#pragma unroll
  for (int i = 0; i < 4; ++i)
    oute[(size_t)(c0 + ty + i * 8) * R + (r0 + tx)] =
        __float2bfloat16(tile[tx][ty + i * 8]);
}

// GEMM1: h[e] = gelu(gather(xb, idx[e]) @ W1t[e]^T + b1[e]);  M=CAP,N=DFF,K=DMODEL
// A: xb rows gathered; B: W1t [e][DFF][DMODEL] (n-major, K contiguous).
// 128x128 tile, BK=64, 4 waves (2x2), 16x16x32 MFMA, global_load_lds w/ XOR swizzle.
__global__ __launch_bounds__(256) void gemm1_kernel(
    const __hip_bfloat16* __restrict__ xb,
    const __hip_bfloat16* __restrict__ W1t,
    const float* __restrict__ b1,
    const int* __restrict__ IDX,
    __hip_bfloat16* __restrict__ h, int e0) {
  __shared__ __align__(16) char smem[32768];
  const int e = e0 + blockIdx.z;
  const int tm = blockIdx.x, tn = blockIdx.y;
  const int tid = threadIdx.x, wave = tid >> 6, lane = tid & 63;

  const char* pA[4]; const char* pB[4];
#pragma unroll
  for (int i = 0; i < 4; ++i) {
    int c = (wave * 4 + i) * 64 + lane;
    int row = c >> 3, sub = c & 7;
    int swz = (sub ^ (row & 7)) << 4;
    int tok = IDX[e * CAP + tm * BM + row];
    pA[i] = (const char*)xb + (size_t)tok * (DMODEL * 2) + swz;
    pB[i] = (const char*)W1t + ((size_t)e * DFF + tn * BN + row) * (DMODEL * 2) + swz;
  }
  f32x4 zero = {0.f, 0.f, 0.f, 0.f};
  f32x4 acc[4][4];
#pragma unroll
  for (int mi = 0; mi < 4; ++mi)
#pragma unroll
    for (int ni = 0; ni < 4; ++ni) acc[mi][ni] = zero;

  const int wm = wave >> 1, wn = wave & 1;
  const int lrow = lane & 15, lgrp = lane >> 4;

  for (int kt = 0; kt < DMODEL / BK; ++kt) {
    if (kt) __syncthreads();
#pragma unroll
    for (int i = 0; i < 4; ++i) {
      gload16(pA[i], smem + (wave * 4 + i) * 1024);
      gload16(pB[i], smem + 16384 + (wave * 4 + i) * 1024);
      pA[i] += BK * 2; pB[i] += BK * 2;
    }
    __syncthreads();
#pragma unroll
    for (int kb = 0; kb < 2; ++kb) {
      bf16x8 af[4], bfr[4];
#pragma unroll
      for (int mi = 0; mi < 4; ++mi) {
        int row = wm * 64 + mi * 16 + lrow;
        int chunk = kb * 4 + lgrp;
        af[mi] = *(const bf16x8*)(smem + row * 128 + ((chunk ^ (row & 7)) << 4));
      }
#pragma unroll
      for (int ni = 0; ni < 4; ++ni) {
        int row = wn * 64 + ni * 16 + lrow;
        int chunk = kb * 4 + lgrp;
        bfr[ni] = *(const bf16x8*)(smem + 16384 + row * 128 + ((chunk ^ (row & 7)) << 4));
      }
#pragma unroll
      for (int mi = 0; mi < 4; ++mi)
#pragma unroll
        for (int ni = 0; ni < 4; ++ni)
          acc[mi][ni] = __builtin_amdgcn_mfma_f32_16x16x32_bf16(
              af[mi], bfr[ni], acc[mi][ni], 0, 0, 0);
    }
  }
  __hip_bfloat16* he = h + (size_t)blockIdx.z * CAP * DFF;
  const float* b1e = b1 + (size_t)e * DFF;
#pragma unroll
  for (int mi = 0; mi < 4; ++mi) {
#pragma unroll
    for (int ni = 0; ni < 4; ++ni) {
      int col = tn * BN + wn * 64 + ni * 16 + lrow;
      float bv = b1e[col];
#pragma unroll
      for (int j = 0; j < 4; ++j) {
        int row = tm * BM + wm * 64 + mi * 16 + lgrp * 4 + j;
        float v = acc[mi][ni][j] + bv;
        v = 0.5f * v * (1.f + erff(v * 0.70710678118654752f));
        he[(size_t)row * DFF + col] = __float2bfloat16(v);
      }
    }
  }
}

// GEMM2: out[idx[e][m]] += G[e][m] * (h[e] @ W2t[e]^T + b2[e]); M=CAP,N=DMODEL,K=DFF
__global__ __launch_bounds__(256) void gemm2_kernel(
    const __hip_bfloat16* __restrict__ h,
    const __hip_bfloat16* __restrict__ W2t,
    const float* __restrict__ b2,
    const int* __restrict__ IDX, const float* __restrict__ G,
    float* __restrict__ out, int e0) {
  __shared__ __align__(16) char smem[32768];
  const int e = e0 + blockIdx.z;
  const int tm = blockIdx.x, tn = blockIdx.y;
  const int tid = threadIdx.x, wave = tid >> 6, lane = tid & 63;

  const char* pA[4]; const char* pB[4];
#pragma unroll
  for (int i = 0; i < 4; ++i) {
    int c = (wave * 4 + i) * 64 + lane;
    int row = c >> 3, sub = c & 7;
    int swz = (sub ^ (row & 7)) << 4;
    pA[i] = (const char*)h + ((size_t)blockIdx.z * CAP + tm * BM + row) * (DFF * 2) + swz;
    pB[i] = (const char*)W2t + ((size_t)e * DMODEL + tn * BN + row) * (DFF * 2) + swz;
  }
  f32x4 zero = {0.f, 0.f, 0.f, 0.f};
  f32x4 acc[4][4];
#pragma unroll
  for (int mi = 0; mi < 4; ++mi)
#pragma unroll
    for (int ni = 0; ni < 4; ++ni) acc[mi][ni] = zero;

  const int wm = wave >> 1, wn = wave & 1;
  const int lrow = lane & 15, lgrp = lane >> 4;

  for (int kt = 0; kt < DFF / BK; ++kt) {
    if (kt) __syncthreads();
#pragma unroll
    for (int i = 0; i < 4; ++i) {
      gload16(pA[i], smem + (wave * 4 + i) * 1024);
      gload16(pB[i], smem + 16384 + (wave * 4 + i) * 1024);
      pA[i] += BK * 2; pB[i] += BK * 2;
    }
    __syncthreads();
#pragma unroll
    for (int kb = 0; kb < 2; ++kb) {
      bf16x8 af[4], bfr[4];
#pragma unroll
      for (int mi = 0; mi < 4; ++mi) {
        int row = wm * 64 + mi * 16 + lrow;
        int chunk = kb * 4 + lgrp;
        af[mi] = *(const bf16x8*)(smem + row * 128 + ((chunk ^ (row & 7)) << 4));
      }
#pragma unroll
      for (int ni = 0; ni < 4; ++ni) {
        int row = wn * 64 + ni * 16 + lrow;
        int chunk = kb * 4 + lgrp;
        bfr[ni] = *(const bf16x8*)(smem + 16384 + row * 128 + ((chunk ^ (row & 7)) << 4));
      }
#pragma unroll
      for (int mi = 0; mi < 4; ++mi)
#pragma unroll
        for (int ni = 0; ni < 4; ++ni)
          acc[mi][ni] = __builtin_amdgcn_mfma_f32_16x16x32_bf16(
              af[mi], bfr[ni], acc[mi][ni], 0, 0, 0);
    }
  }
  const float* b2e = b2 + (size_t)e * DMODEL;
  const int* idxe = IDX + (size_t)e * CAP;
  const float* ge = G + (size_t)e * CAP;
#pragma unroll
  for (int mi = 0; mi < 4; ++mi) {
#pragma unroll
    for (int ni = 0; ni < 4; ++ni) {
      int col = tn * BN + wn * 64 + ni * 16 + lrow;
      float bv = b2e[col];
#pragma unroll
      for (int j = 0; j < 4; ++j) {
        int row = tm * BM + wm * 64 + mi * 16 + lgrp * 4 + j;
        float g = ge[row];
        int tok = idxe[row];
        float v = (acc[mi][ni][j] + bv) * g;
        atomicAdd(out + (size_t)tok * DMODEL + col, v);
      }
    }
  }
}

extern "C" void kernel_launch(void* const* d_in, const int* in_sizes, int n_in,
                              void* d_out, int out_size, void* d_ws, size_t ws_size,
                              hipStream_t stream) {
  const float* x  = (const float*)d_in[0];
  const float* Wr = (const float*)d_in[1];
  const float* W1 = (const float*)d_in[2];
  const float* b1 = (const float*)d_in[3];
  const float* W2 = (const float*)d_in[4];
  const float* b2 = (const float*)d_in[5];
  float* out = (float*)d_out;
  char* ws = (char*)d_ws;

  size_t off = 0;
  float* scoresT = (float*)(ws + off); off += (size_t)NEXP * NTOK * 4;
  float* G       = (float*)(ws + off); off += (size_t)NEXP * CAP * 4;
  int*   IDX     = (int*)(ws + off);   off += (size_t)NEXP * CAP * 4;
  __hip_bfloat16* xb  = (__hip_bfloat16*)(ws + off); off += (size_t)NTOK * DMODEL * 2;
  __hip_bfloat16* W1t = (__hip_bfloat16*)(ws + off); off += (size_t)NEXP * DFF * DMODEL * 2;
  __hip_bfloat16* W2t = (__hip_bfloat16*)(ws + off); off += (size_t)NEXP * DMODEL * DFF * 2;
  __hip_bfloat16* hbuf = (__hip_bfloat16*)(ws + off);
  size_t h_per_e = (size_t)CAP * DFF * 2;
  size_t avail = (ws_size > off) ? (ws_size - off) : 0;
  int EC = (int)(avail / h_per_e);
  if (EC < 1) EC = 1;
  if (EC > NEXP) EC = NEXP;

  zero_f32<<<512, 256, 0, stream>>>(out, out_size / 4);
  router_kernel<<<NTOK / 4, 256, 0, stream>>>(x, Wr, scoresT, xb);
  topk_kernel<<<NEXP, 256, 0, stream>>>(scoresT, G, IDX);
  transpose_cvt<<<dim3(DFF / 32, DMODEL / 32, NEXP), dim3(32, 8), 0, stream>>>(
      W1, W1t, DMODEL, DFF);
  transpose_cvt<<<dim3(DMODEL / 32, DFF / 32, NEXP), dim3(32, 8), 0, stream>>>(
      W2, W2t, DFF, DMODEL);
  for (int e0 = 0; e0 < NEXP; e0 += EC) {
    int ne = (NEXP - e0 < EC) ? (NEXP - e0) : EC;
    gemm1_kernel<<<dim3(CAP / BM, DFF / BN, ne), 256, 0, stream>>>(
        xb, W1t, b1, IDX, hbuf, e0);
    gemm2_kernel<<<dim3(CAP / BM, DMODEL / BN, ne), 256, 0, stream>>>(
        hbuf, W2t, b2, IDX, G, out, e0);
  }
}

// Round 2
// 514.078 us; speedup vs baseline: 1.1616x; 1.1616x over previous
//
#include <hip/hip_runtime.h>
#include <hip/hip_bf16.h>
#include <cstdint>
#include <cstddef>

#define NTOK 8192
#define DMODEL 1024
#define DFF 4096
#define NEXP 8
#define CAP 2048

typedef __attribute__((ext_vector_type(8))) __bf16 bf16x8;
typedef __attribute__((ext_vector_type(4))) float f32x4;

__device__ __forceinline__ void gload16(const void* g, void* l) {
  __builtin_amdgcn_global_load_lds(
      (__attribute__((address_space(1))) void*)(g),
      (__attribute__((address_space(3))) void*)(l),
      16, 0, 0);
}
#define VMWAIT(n) asm volatile("s_waitcnt vmcnt(" #n ")" ::: "memory")

__global__ __launch_bounds__(256) void zero_f32(float* p, int n4) {
  int i = blockIdx.x * blockDim.x + threadIdx.x;
  int stride = gridDim.x * blockDim.x;
  float4 z = make_float4(0.f, 0.f, 0.f, 0.f);
  for (; i < n4; i += stride) ((float4*)p)[i] = z;
}

__global__ __launch_bounds__(256) void router_kernel(
    const float* __restrict__ x, const float* __restrict__ Wr,
    float* __restrict__ scoresT, __hip_bfloat16* __restrict__ xb) {
  const int lane = threadIdx.x & 63;
  const int t = blockIdx.x * 4 + (threadIdx.x >> 6);
  const float* xr = x + (size_t)t * DMODEL;
  float acc[NEXP];
#pragma unroll
  for (int j = 0; j < NEXP; ++j) acc[j] = 0.f;
#pragma unroll
  for (int it = 0; it < DMODEL / 64; ++it) {
    int d = it * 64 + lane;
    float xv = xr[d];
    xb[(size_t)t * DMODEL + d] = __float2bfloat16(xv);
    const float4* w = (const float4*)(Wr + (size_t)d * NEXP);
    float4 w0 = w[0], w1 = w[1];
    acc[0] += xv * w0.x; acc[1] += xv * w0.y; acc[2] += xv * w0.z; acc[3] += xv * w0.w;
    acc[4] += xv * w1.x; acc[5] += xv * w1.y; acc[6] += xv * w1.z; acc[7] += xv * w1.w;
  }
#pragma unroll
  for (int off = 32; off; off >>= 1) {
#pragma unroll
    for (int j = 0; j < NEXP; ++j) acc[j] += __shfl_xor(acc[j], off);
  }
  float m = acc[0];
#pragma unroll
  for (int j = 1; j < NEXP; ++j) m = fmaxf(m, acc[j]);
  float s = 0.f;
#pragma unroll
  for (int j = 0; j < NEXP; ++j) { acc[j] = expf(acc[j] - m); s += acc[j]; }
  float inv = 1.f / s;
  if (lane < NEXP) scoresT[(size_t)lane * NTOK + t] = acc[lane] * inv;
}

__global__ __launch_bounds__(256) void topk_kernel(
    const float* __restrict__ scoresT, float* __restrict__ G, int* __restrict__ IDX) {
  __shared__ uint32_t sb[NTOK];
  __shared__ uint32_t hist[256];
  __shared__ uint32_t s_prefix, s_rem;
  __shared__ uint32_t eq_list[256];
  __shared__ uint32_t eq_cnt, gt_cnt;
  const int e = blockIdx.x, tid = threadIdx.x;
  const float* se = scoresT + (size_t)e * NTOK;
  for (int i = tid; i < NTOK; i += 256) sb[i] = __float_as_uint(se[i]);
  if (tid == 0) { s_prefix = 0u; s_rem = CAP; eq_cnt = 0u; gt_cnt = 0u; }
  __syncthreads();
  for (int r = 0; r < 4; ++r) {
    const int shift = 24 - 8 * r;
    for (int i = tid; i < 256; i += 256) hist[i] = 0u;
    __syncthreads();
    uint32_t pfx = s_prefix;
    for (int i = tid; i < NTOK; i += 256) {
      uint32_t b = sb[i];
      if (((b >> shift) >> 8) == pfx) atomicAdd(&hist[(b >> shift) & 255u], 1u);
    }
    __syncthreads();
    if (tid == 0) {
      uint32_t rem = s_rem, cum = 0u;
      int d = 255;
      for (; d > 0; --d) {
        if (cum + hist[d] >= rem) break;
        cum += hist[d];
      }
      s_prefix = (pfx << 8) | (uint32_t)d;
      s_rem = rem - cum;
    }
    __syncthreads();
  }
  const uint32_t T = s_prefix, need = s_rem;
  for (int i = tid; i < NTOK; i += 256) {
    uint32_t b = sb[i];
    if (b > T) {
      uint32_t p = atomicAdd(&gt_cnt, 1u);
      IDX[(size_t)e * CAP + p] = i;
      G[(size_t)e * CAP + p] = __uint_as_float(b);
    } else if (b == T) {
      uint32_t c = atomicAdd(&eq_cnt, 1u);
      if (c < 256u) eq_list[c] = (uint32_t)i;
    }
  }
  __syncthreads();
  if (tid == 0) {
    uint32_t base = gt_cnt;
    uint32_t c = eq_cnt < 256u ? eq_cnt : 256u;
    for (uint32_t s = 0; s < need; ++s) {
      uint32_t mv = 0xFFFFFFFFu; int mi = 0;
      for (uint32_t j = 0; j < c; ++j)
        if (eq_list[j] < mv) { mv = eq_list[j]; mi = (int)j; }
      eq_list[mi] = 0xFFFFFFFFu;
      IDX[(size_t)e * CAP + base + s] = (int)mv;
      G[(size_t)e * CAP + base + s] = __uint_as_float(T);
    }
  }
}

__global__ __launch_bounds__(256) void transpose_cvt(
    const float* __restrict__ in, __hip_bfloat16* __restrict__ out, int R, int C) {
  __shared__ float tile[32][33];
  const int e = blockIdx.z;
  const float* ine = in + (size_t)e * R * C;
  __hip_bfloat16* oute = out + (size_t)e * R * C;
  const int c0 = blockIdx.x * 32, r0 = blockIdx.y * 32;
  const int tx = threadIdx.x, ty = threadIdx.y;
#pragma unroll
  for (int i = 0; i < 4; ++i)
    tile[ty + i * 8][tx] = ine[(size_t)(r0 + ty + i * 8) * C + (c0 + tx)];
  __syncthreads();
#pragma unroll
  for (int i = 0; i < 4; ++i)
    oute[(size_t)(c0 + ty + i * 8) * R + (r0 + tx)] =
        __float2bfloat16(tile[tx][ty + i * 8]);
}

// ---------------- 256x256 deep-pipelined GEMMs ----------------
// BK=32, 4-deep LDS ring (4 x (16KB A + 16KB B) = 128 KiB), 8 waves (2M x 4N),
// per-wave 128x64 output (acc[8][4] f32x4). One s_barrier per K-tile, counted
// vmcnt(8) gate (tiles t+1,t+2 stay in flight), stage of tile t+3 interleaved
// into tile t's 4 MFMA sub-phases (target buffer = tile t-1, dead after the
// top-of-iter barrier). Quarter swizzle q' = (q + (row>>1))&3 applied on the
// pre-swizzled global source + on ds_read (G21).

#define GEMM_PREAMBLE(NBLK_MASK_TN, TN_BITS)                                   \
  const int tid = threadIdx.x, wave = tid >> 6, lane = tid & 63;               \
  const int wm = wave >> 2, wn = wave & 3;                                     \
  const int lrow = lane & 15, lgrp = lane >> 4;

template <int NT>
__device__ __forceinline__ void gemm_core(
    const char* srcA0, const char* srcA1, const char* srcB0, const char* srcB1,
    int ldsA0, int ldsA1, int ldsB0, int ldsB1,
    const int* offA, const int* offB, char* smem, f32x4 (&acc)[8][4]) {
  const char* sA[2] = {srcA0, srcA1};
  const char* sB[2] = {srcB0, srcB1};
  int lA[2] = {ldsA0, ldsA1};
  int lB[2] = {ldsB0, ldsB1};
#pragma unroll
  for (int t = 0; t < 3; ++t) {
    char* base = smem + t * 32768;
#pragma unroll
    for (int j = 0; j < 2; ++j) {
      gload16(sA[j], base + lA[j]); sA[j] += 64;
      gload16(sB[j], base + lB[j]); sB[j] += 64;
    }
  }
  for (int t = 0; t < NT; ++t) {
    if (t < NT - 2) { VMWAIT(8); }
    else if (t == NT - 2) { VMWAIT(4); }
    else { VMWAIT(0); }
    __builtin_amdgcn_s_barrier();
    asm volatile("" ::: "memory");
    const char* base = smem + (t & 3) * 32768;
    char* sbase = smem + ((t + 3) & 3) * 32768;
    const bool dostage = (t < NT - 3);
    bf16x8 bfr[4];
#pragma unroll
    for (int ni = 0; ni < 4; ++ni) bfr[ni] = *(const bf16x8*)(base + offB[ni]);
#pragma unroll
    for (int p = 0; p < 4; ++p) {
      bf16x8 a0 = *(const bf16x8*)(base + offA[2 * p]);
      bf16x8 a1 = *(const bf16x8*)(base + offA[2 * p + 1]);
      if (p < 2) {
        if (dostage) { gload16(sA[p], sbase + lA[p]); sA[p] += 64; }
      } else {
        if (dostage) { gload16(sB[p - 2], sbase + lB[p - 2]); sB[p - 2] += 64; }
      }
      __builtin_amdgcn_s_setprio(1);
#pragma unroll
      for (int ni = 0; ni < 4; ++ni) {
        acc[2 * p][ni] = __builtin_amdgcn_mfma_f32_16x16x32_bf16(
            a0, bfr[ni], acc[2 * p][ni], 0, 0, 0);
        acc[2 * p + 1][ni] = __builtin_amdgcn_mfma_f32_16x16x32_bf16(
            a1, bfr[ni], acc[2 * p + 1][ni], 0, 0, 0);
      }
      __builtin_amdgcn_s_setprio(0);
    }
  }
}

__global__ __launch_bounds__(512, 2) void gemm1_kernel(
    const __hip_bfloat16* __restrict__ xb,
    const __hip_bfloat16* __restrict__ W1t,
    const float* __restrict__ b1,
    const int* __restrict__ IDX,
    __hip_bfloat16* __restrict__ h, int e0, int nblk) {
  __shared__ __align__(16) char smem[131072];
  int lin = blockIdx.x;
  { int q = nblk >> 3; lin = (lin & 7) * q + (lin >> 3); }  // XCD-contiguous
  const int tm = lin & 7, tn = (lin >> 3) & 15, ez = lin >> 7;
  const int e = e0 + ez;
  GEMM_PREAMBLE(15, 4)

  const char* srcA[2]; const char* srcB[2];
  int lA[2], lB[2];
#pragma unroll
  for (int j = 0; j < 2; ++j) {
    int chunk = j * 8 + wave;
    int slot = chunk * 64 + lane;
    int r = slot >> 2, qp = slot & 3;
    int q = (qp - (r >> 1)) & 3;
    lA[j] = chunk * 1024;
    lB[j] = 16384 + chunk * 1024;
    int tok = IDX[e * CAP + tm * 256 + r];
    srcA[j] = (const char*)(xb + (size_t)tok * DMODEL + q * 8);
    srcB[j] = (const char*)(W1t + ((size_t)e * DFF + tn * 256 + r) * DMODEL + q * 8);
  }
  int offA[8], offB[4];
#pragma unroll
  for (int mi = 0; mi < 8; ++mi) {
    int rr = wm * 128 + mi * 16 + lrow;
    offA[mi] = rr * 64 + ((lgrp + (rr >> 1)) & 3) * 16;
  }
#pragma unroll
  for (int ni = 0; ni < 4; ++ni) {
    int rr = wn * 64 + ni * 16 + lrow;
    offB[ni] = 16384 + rr * 64 + ((lgrp + (rr >> 1)) & 3) * 16;
  }
  f32x4 acc[8][4];
  f32x4 zero = {0.f, 0.f, 0.f, 0.f};
#pragma unroll
  for (int mi = 0; mi < 8; ++mi)
#pragma unroll
    for (int ni = 0; ni < 4; ++ni) acc[mi][ni] = zero;

  gemm_core<DMODEL / 32>(srcA[0], srcA[1], srcB[0], srcB[1],
                         lA[0], lA[1], lB[0], lB[1], offA, offB, smem, acc);

  __hip_bfloat16* he = h + (size_t)ez * CAP * DFF;
  const float* b1e = b1 + (size_t)e * DFF;
  float bvals[4];
#pragma unroll
  for (int ni = 0; ni < 4; ++ni)
    bvals[ni] = b1e[tn * 256 + wn * 64 + ni * 16 + lrow];
#pragma unroll
  for (int mi = 0; mi < 8; ++mi) {
#pragma unroll
    for (int j = 0; j < 4; ++j) {
      int row = tm * 256 + wm * 128 + mi * 16 + lgrp * 4 + j;
      __hip_bfloat16* hrow = he + (size_t)row * DFF;
#pragma unroll
      for (int ni = 0; ni < 4; ++ni) {
        int col = tn * 256 + wn * 64 + ni * 16 + lrow;
        float v = acc[mi][ni][j] + bvals[ni];
        v = 0.5f * v * (1.f + erff(v * 0.70710678118654752f));
        hrow[col] = __float2bfloat16(v);
      }
    }
  }
}

__global__ __launch_bounds__(512, 2) void gemm2_kernel(
    const __hip_bfloat16* __restrict__ h,
    const __hip_bfloat16* __restrict__ W2t,
    const float* __restrict__ b2,
    const int* __restrict__ IDX, const float* __restrict__ G,
    float* __restrict__ out, int e0, int nblk) {
  __shared__ __align__(16) char smem[131072];
  int lin = blockIdx.x;
  { int q = nblk >> 3; lin = (lin & 7) * q + (lin >> 3); }
  const int tm = lin & 7, tn = (lin >> 3) & 3, ez = lin >> 5;
  const int e = e0 + ez;
  GEMM_PREAMBLE(3, 2)

  const char* srcA[2]; const char* srcB[2];
  int lA[2], lB[2];
#pragma unroll
  for (int j = 0; j < 2; ++j) {
    int chunk = j * 8 + wave;
    int slot = chunk * 64 + lane;
    int r = slot >> 2, qp = slot & 3;
    int q = (qp - (r >> 1)) & 3;
    lA[j] = chunk * 1024;
    lB[j] = 16384 + chunk * 1024;
    srcA[j] = (const char*)(h + ((size_t)ez * CAP + tm * 256 + r) * DFF + q * 8);
    srcB[j] = (const char*)(W2t + ((size_t)e * DMODEL + tn * 256 + r) * DFF + q * 8);
  }
  int offA[8], offB[4];
#pragma unroll
  for (int mi = 0; mi < 8; ++mi) {
    int rr = wm * 128 + mi * 16 + lrow;
    offA[mi] = rr * 64 + ((lgrp + (rr >> 1)) & 3) * 16;
  }
#pragma unroll
  for (int ni = 0; ni < 4; ++ni) {
    int rr = wn * 64 + ni * 16 + lrow;
    offB[ni] = 16384 + rr * 64 + ((lgrp + (rr >> 1)) & 3) * 16;
  }
  f32x4 acc[8][4];
  f32x4 zero = {0.f, 0.f, 0.f, 0.f};
#pragma unroll
  for (int mi = 0; mi < 8; ++mi)
#pragma unroll
    for (int ni = 0; ni < 4; ++ni) acc[mi][ni] = zero;

  gemm_core<DFF / 32>(srcA[0], srcA[1], srcB[0], srcB[1],
                      lA[0], lA[1], lB[0], lB[1], offA, offB, smem, acc);

  const float* b2e = b2 + (size_t)e * DMODEL;
  const int* idxe = IDX + (size_t)e * CAP;
  const float* ge = G + (size_t)e * CAP;
  float bvals[4];
#pragma unroll
  for (int ni = 0; ni < 4; ++ni)
    bvals[ni] = b2e[tn * 256 + wn * 64 + ni * 16 + lrow];
#pragma unroll
  for (int mi = 0; mi < 8; ++mi) {
#pragma unroll
    for (int j = 0; j < 4; ++j) {
      int row = tm * 256 + wm * 128 + mi * 16 + lgrp * 4 + j;
      float g = ge[row];
      int tok = idxe[row];
      float* orow = out + (size_t)tok * DMODEL;
#pragma unroll
      for (int ni = 0; ni < 4; ++ni) {
        int col = tn * 256 + wn * 64 + ni * 16 + lrow;
        atomicAdd(orow + col, (acc[mi][ni][j] + bvals[ni]) * g);
      }
    }
  }
}

extern "C" void kernel_launch(void* const* d_in, const int* in_sizes, int n_in,
                              void* d_out, int out_size, void* d_ws, size_t ws_size,
                              hipStream_t stream) {
  const float* x  = (const float*)d_in[0];
  const float* Wr = (const float*)d_in[1];
  const float* W1 = (const float*)d_in[2];
  const float* b1 = (const float*)d_in[3];
  const float* W2 = (const float*)d_in[4];
  const float* b2 = (const float*)d_in[5];
  float* out = (float*)d_out;
  char* ws = (char*)d_ws;

  size_t off = 0;
  float* scoresT = (float*)(ws + off); off += (size_t)NEXP * NTOK * 4;
  float* G       = (float*)(ws + off); off += (size_t)NEXP * CAP * 4;
  int*   IDX     = (int*)(ws + off);   off += (size_t)NEXP * CAP * 4;
  __hip_bfloat16* xb  = (__hip_bfloat16*)(ws + off); off += (size_t)NTOK * DMODEL * 2;
  __hip_bfloat16* W1t = (__hip_bfloat16*)(ws + off); off += (size_t)NEXP * DFF * DMODEL * 2;
  __hip_bfloat16* W2t = (__hip_bfloat16*)(ws + off); off += (size_t)NEXP * DMODEL * DFF * 2;
  __hip_bfloat16* hbuf = (__hip_bfloat16*)(ws + off);
  size_t h_per_e = (size_t)CAP * DFF * 2;
  size_t avail = (ws_size > off) ? (ws_size - off) : 0;
  int EC = (int)(avail / h_per_e);
  if (EC < 1) EC = 1;
  if (EC > NEXP) EC = NEXP;

  zero_f32<<<512, 256, 0, stream>>>(out, out_size / 4);
  router_kernel<<<NTOK / 4, 256, 0, stream>>>(x, Wr, scoresT, xb);
  topk_kernel<<<NEXP, 256, 0, stream>>>(scoresT, G, IDX);
  transpose_cvt<<<dim3(DFF / 32, DMODEL / 32, NEXP), dim3(32, 8), 0, stream>>>(
      W1, W1t, DMODEL, DFF);
  transpose_cvt<<<dim3(DMODEL / 32, DFF / 32, NEXP), dim3(32, 8), 0, stream>>>(
      W2, W2t, DFF, DMODEL);
  for (int e0 = 0; e0 < NEXP; e0 += EC) {
    int ne = (NEXP - e0 < EC) ? (NEXP - e0) : EC;
    int nblk1 = 128 * ne;
    gemm1_kernel<<<nblk1, 512, 0, stream>>>(xb, W1t, b1, IDX, hbuf, e0, nblk1);
    int nblk2 = 32 * ne;
    gemm2_kernel<<<nblk2, 512, 0, stream>>>(hbuf, W2t, b2, IDX, G, out, e0, nblk2);
  }
}